// Round 18
// baseline (87.472 us; speedup 1.0000x reference)
//
#include <hip/hip_runtime.h>
#include <hip/hip_bf16.h>

#define N_NODES  100000
#define N_EDGES  6400000
#define N_GRAPHS 512
#define HID      64
#define OUT_DIM  128

// binning params (64-node bins)
#define BIN_SHIFT 6
#define BIN_NODES 64
#define NB 1563                            // ceil(100000/64)
#define CAP 5120                           // slots per bin (mean 4096, +16 sigma)
#define MAXSEG 4

// scatter params (512 fat blocks)
#define SCB 512
#define SCT 1024
#define SCH (N_EDGES / SCB)                // 12500 exactly
#define SEGB ((NB + 15) / 16)              // 98 bins per wave segment
#define ITERS 13                           // ceil(12500/1024)

// consumer params
#define BMT 512
#define NW  8
#define C4 3                               // uint4 loads: 3*2048*4 covers CAP

// ---------------------------------------------------------------------------
// Kernel S (r13 producer, unchanged — measured-best): block counting-sort by
// dst bin, src/dst in registers, two LDS atomic passes, coalesced run copy.
// ---------------------------------------------------------------------------
__global__ void __launch_bounds__(SCT)
scatter_bin(const int* __restrict__ src, const int* __restrict__ dst,
            unsigned int* __restrict__ cursor, unsigned int* __restrict__ binned) {
    __shared__ unsigned int hist[NB];      // counts -> excl base -> run cnt -> incl
    __shared__ unsigned int gbase[NB];
    __shared__ unsigned int sorted[SCH];   // 50 KB
    __shared__ unsigned int wtot[16];

    const int tid = threadIdx.x, lane = tid & 63, w = tid >> 6;
    const int e0 = blockIdx.x * SCH;

    int dreg[ITERS], sreg[ITERS];
    #pragma unroll
    for (int k = 0; k < ITERS; ++k) {
        int idx = k * SCT + tid;
        if (idx < SCH) { dreg[k] = dst[e0 + idx]; sreg[k] = src[e0 + idx]; }
        else           { dreg[k] = -1;            sreg[k] = 0; }
    }

    for (int i = tid; i < NB; i += SCT) hist[i] = 0u;
    __syncthreads();

    // A) histogram (plain atomic)
    #pragma unroll
    for (int k = 0; k < ITERS; ++k)
        if (dreg[k] >= 0) atomicAdd(&hist[dreg[k] >> BIN_SHIFT], 1u);
    __syncthreads();

    // B) exclusive scan + reserve global ranges
    const int s0 = w * SEGB;
    const int s1 = min(s0 + SEGB, NB);
    unsigned int carry = 0u;
    for (int base = s0; base < s1; base += 64) {
        int i = base + lane;
        bool ok = (i < s1);
        unsigned int v = ok ? hist[i] : 0u;
        if (ok && v)
            gbase[i] = (unsigned int)i * CAP + atomicAdd(&cursor[i], v);
        unsigned int xi = v;
        #pragma unroll
        for (int d = 1; d < 64; d <<= 1) {
            unsigned int u = __shfl_up(xi, d, 64);
            if (lane >= d) xi += u;
        }
        if (ok) hist[i] = carry + xi - v;
        carry += __shfl(xi, 63, 64);
    }
    if (lane == 0) wtot[w] = carry;
    __syncthreads();
    if (w == 0 && lane < 16) {
        unsigned int v = wtot[lane], xi = v;
        #pragma unroll
        for (int d = 1; d < 16; d <<= 1) {
            unsigned int u = __shfl_up(xi, d, 64);
            if (lane >= d) xi += u;
        }
        wtot[lane] = xi - v;
    }
    __syncthreads();
    {
        unsigned int woff = wtot[w];
        for (int i = s0 + lane; i < s1; i += 64) hist[i] += woff;
    }
    __syncthreads();

    // C) reorder into LDS
    #pragma unroll
    for (int k = 0; k < ITERS; ++k) {
        if (dreg[k] >= 0) {
            int b = dreg[k] >> BIN_SHIFT;
            unsigned int slot = atomicAdd(&hist[b], 1u);
            sorted[slot] = ((unsigned int)sreg[k] << BIN_SHIFT)
                         | (unsigned int)(dreg[k] & (BIN_NODES - 1));
        }
    }
    __syncthreads();

    // D) coalesced run copy
    const int sub = lane >> 3, le = lane & 7;
    for (int bb = s0 + sub; bb < s1; bb += 8) {
        unsigned int lo = (bb == 0) ? 0u : hist[bb - 1];
        unsigned int hi = hist[bb];
        unsigned int len = hi - lo;
        if (len == 0u) continue;
        unsigned int gb  = gbase[bb];
        unsigned int end = (unsigned int)(bb + 1) * CAP;
        for (unsigned int t = le; t < len; t += 8)
            if (gb + t < end) binned[gb + t] = sorted[lo + t];
    }
}

// ---------------------------------------------------------------------------
// Kernel B (r17 consumer + EARLY LOAD ISSUE): cursor + payload uint4 loads
// issue unconditionally at kernel start (workspace pad covers the over-read),
// overlapping their L2 latency with the LDS init. Rest identical to r17.
// ---------------------------------------------------------------------------
__global__ void __launch_bounds__(BMT)
bin_mlp_pool(const unsigned int* __restrict__ binned,
             const unsigned int* __restrict__ cursor,
             const float* __restrict__ x, const int* __restrict__ batch,
             const float* __restrict__ W1, const float* __restrict__ b1,
             float* __restrict__ gsum, float* __restrict__ gcnt) {
    const int b   = blockIdx.x;
    const int n0  = b << BIN_SHIFT;
    const int tid = threadIdx.x;
    const int lane = tid & 63;
    const int w    = tid >> 6;          // wave 0..7

    __shared__ unsigned int hist[BIN_NODES];
    __shared__ unsigned int off[BIN_NODES + 1];
    __shared__ unsigned int ssrc[CAP];                  // 20 KB
    __shared__ float lagg[BIN_NODES][4];
    __shared__ float psum[NW][MAXSEG][HID];             // 8 KB, wave-private
    __shared__ float pcnt[NW][MAXSEG];

    // --- issue ALL global loads first (no LDS dependency; pad covers OOB) ---
    const unsigned int cnt_raw = cursor[b];
    const unsigned int* bp = binned + (size_t)b * CAP;
    uint4 v4[C4];
    #pragma unroll
    for (int k = 0; k < C4; ++k) {
        unsigned int i0 = (unsigned int)k * (BMT * 4) + (unsigned int)(tid << 2);
        v4[k] = *reinterpret_cast<const uint4*>(bp + i0);   // unconditional
    }
    const int base_g = batch[n0];

    // --- LDS init overlaps the in-flight loads ---
    if (tid < BIN_NODES) hist[tid] = 0u;
    for (int i = tid; i < NW * MAXSEG * HID; i += BMT) ((float*)psum)[i] = 0.0f;
    if (tid < NW * MAXSEG) ((float*)pcnt)[tid] = 0.0f;
    __syncthreads();

    unsigned int cnt = cnt_raw > CAP ? CAP : cnt_raw;   // safety clamp

    // 1) histogram; rank packed into bits 23..31
    unsigned int breg[C4][4];
    #pragma unroll
    for (int k = 0; k < C4; ++k) {
        unsigned int i0 = (unsigned int)k * (BMT * 4) + (unsigned int)(tid << 2);
        breg[k][0] = v4[k].x; breg[k][1] = v4[k].y;
        breg[k][2] = v4[k].z; breg[k][3] = v4[k].w;
        #pragma unroll
        for (int j = 0; j < 4; ++j) {
            if (i0 + j < cnt) {
                unsigned int r = atomicAdd(&hist[breg[k][j] & (BIN_NODES - 1)], 1u);
                breg[k][j] |= (r << 23);
            } else breg[k][j] = 0xFFFFFFFFu;
        }
    }
    __syncthreads();

    // 2) prefix scan (wave 0): off[dl] = exclusive base
    if (tid < BIN_NODES) {
        unsigned int v = hist[tid];
        #pragma unroll
        for (int d = 1; d < 64; d <<= 1) {
            unsigned int u = __shfl_up(v, d, 64);
            if (lane >= d) v += u;
        }
        off[tid + 1] = v;
        if (tid == 0) off[0] = 0u;
    }
    __syncthreads();

    // 3) reorder src into node-grouped LDS: computed write, no atomic
    #pragma unroll
    for (int k = 0; k < C4; ++k)
        #pragma unroll
        for (int j = 0; j < 4; ++j) {
            unsigned int e = breg[k][j];
            if (e != 0xFFFFFFFFu) {
                unsigned int dl   = e & (BIN_NODES - 1);
                unsigned int rank = (e >> 23);
                ssrc[off[dl] + rank] = (e >> BIN_SHIFT) & 0x1FFFFu;
            }
        }
    __syncthreads();

    // 4) per-node gather + reduce: 4 nodes concurrently per wave (16-lane grp)
    {
        const int sub = lane >> 4, sl = lane & 15;
        #pragma unroll
        for (int r = 0; r < 2; ++r) {
            int dl = w * 8 + r * 4 + sub;           // wave w owns nodes w*8..w*8+7
            unsigned int o0 = off[dl], o1 = off[dl + 1];
            float a0 = 0.f, a1 = 0.f, a2 = 0.f, a3 = 0.f;
            for (unsigned int i = o0 + sl; i < o1; i += 16) {
                unsigned int s = ssrc[i];
                float4 xv = *reinterpret_cast<const float4*>(x + (size_t)s * 4);
                a0 += xv.x; a1 += xv.y; a2 += xv.z; a3 += xv.w;
            }
            #pragma unroll
            for (int d = 8; d >= 1; d >>= 1) {
                a0 += __shfl_xor(a0, d, 16);
                a1 += __shfl_xor(a1, d, 16);
                a2 += __shfl_xor(a2, d, 16);
                a3 += __shfl_xor(a3, d, 16);
            }
            if (sl == 0) {
                lagg[dl][0] = a0; lagg[dl][1] = a1;
                lagg[dl][2] = a2; lagg[dl][3] = a3;
            }
        }
    }
    __syncthreads();

    // 5) MLP + pool (lane = hidden col j; wave w owns nodes w*8..w*8+7)
    const int j = lane;
    const float w1c0 = W1[0 * HID + j], w1c1 = W1[1 * HID + j];
    const float w1c2 = W1[2 * HID + j], w1c3 = W1[3 * HID + j];
    const float b1j = b1[j];

    for (int vl = w * 8; vl < w * 8 + 8; ++vl) {
        int v = n0 + vl;
        if (v >= N_NODES) break;
        float xa0 = x[(size_t)v * 4 + 0] + lagg[vl][0];
        float xa1 = x[(size_t)v * 4 + 1] + lagg[vl][1];
        float xa2 = x[(size_t)v * 4 + 2] + lagg[vl][2];
        float xa3 = x[(size_t)v * 4 + 3] + lagg[vl][3];
        float h = b1j;
        h = fmaf(xa0, w1c0, h);
        h = fmaf(xa1, w1c1, h);
        h = fmaf(xa2, w1c2, h);
        h = fmaf(xa3, w1c3, h);
        h = fmaxf(h, 0.0f);
        int g = batch[v];
        int seg = g - base_g;
        if (seg < MAXSEG) {
            psum[w][seg][j] += h;                 // wave-private: no race
            if (j == 0) pcnt[w][seg] += 1.0f;
        } else {                                  // pathological span
            unsafeAtomicAdd(&gsum[(size_t)g * HID + j], h);
            if (j == 0) unsafeAtomicAdd(&gcnt[g], 1.0f);
        }
    }
    __syncthreads();

    // flush: waves 0..3 each own one segment, summing all 8 replicas
    if (w < MAXSEG) {
        int seg = w;
        float v8 = 0.0f;
        #pragma unroll
        for (int r = 0; r < NW; ++r) v8 += psum[r][seg][j];
        if (v8 != 0.0f)
            unsafeAtomicAdd(&gsum[(size_t)(base_g + seg) * HID + j], v8);
    }
    if (tid < MAXSEG) {
        float c = 0.0f;
        #pragma unroll
        for (int r = 0; r < NW; ++r) c += pcnt[r][tid];
        if (c > 0.0f)
            unsafeAtomicAdd(&gcnt[base_g + tid], c);
    }
}

// ---------------------------------------------------------------------------
// Kernel C: per graph g (W2/head hoisted past the mean pool by linearity).
// ---------------------------------------------------------------------------
__global__ void finalize(const float* __restrict__ gsum, const float* __restrict__ gcnt,
                         const float* __restrict__ W2, const float* __restrict__ b2,
                         const float* __restrict__ Wlin, const float* __restrict__ blin,
                         float* __restrict__ out) {
    int g = blockIdx.x;
    int j = threadIdx.x;  // 0..127
    __shared__ float pooled[HID];

    float cnt = gcnt[g];
    float inv = 1.0f / fmaxf(cnt, 1.0f);

    if (j < HID) {
        float s = cnt * b2[j];
        #pragma unroll 8
        for (int k = 0; k < HID; ++k)
            s = fmaf(gsum[(size_t)g * HID + k], W2[k * HID + j], s);
        pooled[j] = s * inv;
    }
    __syncthreads();

    float o = blin[j];
    #pragma unroll 8
    for (int k = 0; k < HID; ++k)
        o = fmaf(pooled[k], Wlin[k * OUT_DIM + j], o);
    out[(size_t)g * OUT_DIM + j] = o;
}

// ------------------------- fallback (round-2) path -------------------------
__global__ void edge_scatter(const int* __restrict__ src, const int* __restrict__ dst,
                             const float* __restrict__ x, float* __restrict__ agg) {
    int stride = gridDim.x * blockDim.x;
    for (int e = blockIdx.x * blockDim.x + threadIdx.x; e < N_EDGES; e += stride) {
        int s = src[e];
        int d = dst[e];
        float4 xv = *reinterpret_cast<const float4*>(x + (size_t)s * 4);
        float* a = agg + (size_t)d * 4;
        unsafeAtomicAdd(a + 0, xv.x);
        unsafeAtomicAdd(a + 1, xv.y);
        unsafeAtomicAdd(a + 2, xv.z);
        unsafeAtomicAdd(a + 3, xv.w);
    }
}

__global__ void node_mlp_pool(const float* __restrict__ x, const float* __restrict__ agg,
                              const int* __restrict__ batch,
                              const float* __restrict__ W1, const float* __restrict__ b1,
                              float* __restrict__ gsum, float* __restrict__ gcnt) {
    int j = threadIdx.x & 63;
    int local = threadIdx.x >> 6;
    int v = blockIdx.x * 4 + local;
    if (v >= N_NODES) return;
    float4 xv = *reinterpret_cast<const float4*>(x + (size_t)v * 4);
    float4 av = *reinterpret_cast<const float4*>(agg + (size_t)v * 4);
    float h = b1[j];
    h = fmaf(xv.x + av.x, W1[0 * HID + j], h);
    h = fmaf(xv.y + av.y, W1[1 * HID + j], h);
    h = fmaf(xv.z + av.z, W1[2 * HID + j], h);
    h = fmaf(xv.w + av.w, W1[3 * HID + j], h);
    h = fmaxf(h, 0.0f);
    int g = batch[v];
    unsafeAtomicAdd(&gsum[(size_t)g * HID + j], h);
    if (j == 0) unsafeAtomicAdd(&gcnt[g], 1.0f);
}

extern "C" void kernel_launch(void* const* d_in, const int* in_sizes, int n_in,
                              void* d_out, int out_size, void* d_ws, size_t ws_size,
                              hipStream_t stream) {
    const float* x    = (const float*)d_in[0];
    const int*   ei   = (const int*)d_in[1];
    const int*   bat  = (const int*)d_in[2];
    const float* W1   = (const float*)d_in[3];
    const float* b1   = (const float*)d_in[4];
    const float* W2   = (const float*)d_in[5];
    const float* b2   = (const float*)d_in[6];
    const float* Wlin = (const float*)d_in[7];
    const float* blin = (const float*)d_in[8];
    float* out = (float*)d_out;

    const int* src  = ei;             // edge_index[0]
    const int* dstp = ei + N_EDGES;   // edge_index[1]

    char* ws = (char*)d_ws;
    // layout: gsum[131072] gcnt[2048] cursor[6252 -> pad 6272] binned[NB*CAP*4] pad[16K]
    const size_t GSUM_OFF = 0, GCNT_OFF = 131072, CUR_OFF = 133120, BIN_OFF = 139392;
    const size_t NEED = BIN_OFF + (size_t)NB * CAP * 4 + 16384;   // ~32.2 MB

    if (ws_size >= NEED) {
        float* gsum = (float*)(ws + GSUM_OFF);
        float* gcnt = (float*)(ws + GCNT_OFF);
        unsigned int* cursor = (unsigned int*)(ws + CUR_OFF);
        unsigned int* binned = (unsigned int*)(ws + BIN_OFF);

        hipMemsetAsync(d_ws, 0, BIN_OFF, stream);  // gsum+gcnt+cursor

        scatter_bin<<<SCB, SCT, 0, stream>>>(src, dstp, cursor, binned);
        bin_mlp_pool<<<NB, BMT, 0, stream>>>(binned, cursor, x, bat, W1, b1, gsum, gcnt);
        finalize<<<N_GRAPHS, OUT_DIM, 0, stream>>>(gsum, gcnt, W2, b2, Wlin, blin, out);
    } else {
        // fallback: round-2 pipeline (needs ~1.74 MB)
        float* agg  = (float*)(ws);
        float* gsum = (float*)(ws + 1600000);
        float* gcnt = (float*)(ws + 1600000 + 131072);
        hipMemsetAsync(d_ws, 0, 1600000 + 131072 + 2048, stream);
        edge_scatter<<<4096, 256, 0, stream>>>(src, dstp, x, agg);
        node_mlp_pool<<<(N_NODES + 3) / 4, 256, 0, stream>>>(x, agg, bat, W1, b1, gsum, gcnt);
        finalize<<<N_GRAPHS, OUT_DIM, 0, stream>>>(gsum, gcnt, W2, b2, Wlin, blin, out);
    }
}

// Round 19
// 85.107 us; speedup vs baseline: 1.0278x; 1.0278x over previous
//
#include <hip/hip_runtime.h>
#include <hip/hip_bf16.h>

#define N_NODES  100000
#define N_EDGES  6400000
#define N_GRAPHS 512
#define HID      64
#define OUT_DIM  128

// binning params (64-node bins)
#define BIN_SHIFT 6
#define BIN_NODES 64
#define NB 1563                            // ceil(100000/64)
#define CAP 5120                           // slots per bin (mean 4096, +16 sigma)
#define MAXSEG 4

// scatter params (512 fat blocks)
#define SCB 512
#define SCT 1024
#define SCH (N_EDGES / SCB)                // 12500 exactly
#define SEGB ((NB + 15) / 16)              // 98 bins per wave segment
#define ITERS 13                           // ceil(12500/1024)

// consumer params
#define BMT 512
#define NW  8
#define C4 3                               // uint4 loads: 3*2048*4 covers CAP

// ---------------------------------------------------------------------------
// Kernel S (r13 producer, unchanged — measured-best): block counting-sort by
// dst bin, src/dst in registers, two LDS atomic passes, coalesced run copy.
// ---------------------------------------------------------------------------
__global__ void __launch_bounds__(SCT)
scatter_bin(const int* __restrict__ src, const int* __restrict__ dst,
            unsigned int* __restrict__ cursor, unsigned int* __restrict__ binned) {
    __shared__ unsigned int hist[NB];      // counts -> excl base -> run cnt -> incl
    __shared__ unsigned int gbase[NB];
    __shared__ unsigned int sorted[SCH];   // 50 KB
    __shared__ unsigned int wtot[16];

    const int tid = threadIdx.x, lane = tid & 63, w = tid >> 6;
    const int e0 = blockIdx.x * SCH;

    int dreg[ITERS], sreg[ITERS];
    #pragma unroll
    for (int k = 0; k < ITERS; ++k) {
        int idx = k * SCT + tid;
        if (idx < SCH) { dreg[k] = dst[e0 + idx]; sreg[k] = src[e0 + idx]; }
        else           { dreg[k] = -1;            sreg[k] = 0; }
    }

    for (int i = tid; i < NB; i += SCT) hist[i] = 0u;
    __syncthreads();

    // A) histogram (plain atomic)
    #pragma unroll
    for (int k = 0; k < ITERS; ++k)
        if (dreg[k] >= 0) atomicAdd(&hist[dreg[k] >> BIN_SHIFT], 1u);
    __syncthreads();

    // B) exclusive scan + reserve global ranges
    const int s0 = w * SEGB;
    const int s1 = min(s0 + SEGB, NB);
    unsigned int carry = 0u;
    for (int base = s0; base < s1; base += 64) {
        int i = base + lane;
        bool ok = (i < s1);
        unsigned int v = ok ? hist[i] : 0u;
        if (ok && v)
            gbase[i] = (unsigned int)i * CAP + atomicAdd(&cursor[i], v);
        unsigned int xi = v;
        #pragma unroll
        for (int d = 1; d < 64; d <<= 1) {
            unsigned int u = __shfl_up(xi, d, 64);
            if (lane >= d) xi += u;
        }
        if (ok) hist[i] = carry + xi - v;
        carry += __shfl(xi, 63, 64);
    }
    if (lane == 0) wtot[w] = carry;
    __syncthreads();
    if (w == 0 && lane < 16) {
        unsigned int v = wtot[lane], xi = v;
        #pragma unroll
        for (int d = 1; d < 16; d <<= 1) {
            unsigned int u = __shfl_up(xi, d, 64);
            if (lane >= d) xi += u;
        }
        wtot[lane] = xi - v;
    }
    __syncthreads();
    {
        unsigned int woff = wtot[w];
        for (int i = s0 + lane; i < s1; i += 64) hist[i] += woff;
    }
    __syncthreads();

    // C) reorder into LDS
    #pragma unroll
    for (int k = 0; k < ITERS; ++k) {
        if (dreg[k] >= 0) {
            int b = dreg[k] >> BIN_SHIFT;
            unsigned int slot = atomicAdd(&hist[b], 1u);
            sorted[slot] = ((unsigned int)sreg[k] << BIN_SHIFT)
                         | (unsigned int)(dreg[k] & (BIN_NODES - 1));
        }
    }
    __syncthreads();

    // D) coalesced run copy
    const int sub = lane >> 3, le = lane & 7;
    for (int bb = s0 + sub; bb < s1; bb += 8) {
        unsigned int lo = (bb == 0) ? 0u : hist[bb - 1];
        unsigned int hi = hist[bb];
        unsigned int len = hi - lo;
        if (len == 0u) continue;
        unsigned int gb  = gbase[bb];
        unsigned int end = (unsigned int)(bb + 1) * CAP;
        for (unsigned int t = le; t < len; t += 8)
            if (gb + t < end) binned[gb + t] = sorted[lo + t];
    }
}

// ---------------------------------------------------------------------------
// Kernel B (r18 consumer + gather unroll + seg-uniform pool fast path).
// ---------------------------------------------------------------------------
__global__ void __launch_bounds__(BMT)
bin_mlp_pool(const unsigned int* __restrict__ binned,
             const unsigned int* __restrict__ cursor,
             const float* __restrict__ x, const int* __restrict__ batch,
             const float* __restrict__ W1, const float* __restrict__ b1,
             float* __restrict__ gsum, float* __restrict__ gcnt) {
    const int b   = blockIdx.x;
    const int n0  = b << BIN_SHIFT;
    const int tid = threadIdx.x;
    const int lane = tid & 63;
    const int w    = tid >> 6;          // wave 0..7

    __shared__ unsigned int hist[BIN_NODES];
    __shared__ unsigned int off[BIN_NODES + 1];
    __shared__ unsigned int ssrc[CAP];                  // 20 KB
    __shared__ float lagg[BIN_NODES][4];
    __shared__ float psum[NW][MAXSEG][HID];             // 8 KB, wave-private
    __shared__ float pcnt[NW][MAXSEG];

    // --- issue ALL global loads first (pad covers the over-read) ---
    const unsigned int cnt_raw = cursor[b];
    const unsigned int* bp = binned + (size_t)b * CAP;
    uint4 v4[C4];
    #pragma unroll
    for (int k = 0; k < C4; ++k) {
        unsigned int i0 = (unsigned int)k * (BMT * 4) + (unsigned int)(tid << 2);
        v4[k] = *reinterpret_cast<const uint4*>(bp + i0);   // unconditional
    }
    const int base_g = batch[n0];

    // --- LDS init overlaps the in-flight loads ---
    if (tid < BIN_NODES) hist[tid] = 0u;
    for (int i = tid; i < NW * MAXSEG * HID; i += BMT) ((float*)psum)[i] = 0.0f;
    if (tid < NW * MAXSEG) ((float*)pcnt)[tid] = 0.0f;
    __syncthreads();

    unsigned int cnt = cnt_raw > CAP ? CAP : cnt_raw;   // safety clamp

    // 1) histogram; rank packed into bits 23..31
    unsigned int breg[C4][4];
    #pragma unroll
    for (int k = 0; k < C4; ++k) {
        unsigned int i0 = (unsigned int)k * (BMT * 4) + (unsigned int)(tid << 2);
        breg[k][0] = v4[k].x; breg[k][1] = v4[k].y;
        breg[k][2] = v4[k].z; breg[k][3] = v4[k].w;
        #pragma unroll
        for (int j = 0; j < 4; ++j) {
            if (i0 + j < cnt) {
                unsigned int r = atomicAdd(&hist[breg[k][j] & (BIN_NODES - 1)], 1u);
                breg[k][j] |= (r << 23);
            } else breg[k][j] = 0xFFFFFFFFu;
        }
    }
    __syncthreads();

    // 2) prefix scan (wave 0): off[dl] = exclusive base
    if (tid < BIN_NODES) {
        unsigned int v = hist[tid];
        #pragma unroll
        for (int d = 1; d < 64; d <<= 1) {
            unsigned int u = __shfl_up(v, d, 64);
            if (lane >= d) v += u;
        }
        off[tid + 1] = v;
        if (tid == 0) off[0] = 0u;
    }
    __syncthreads();

    // 3) reorder src into node-grouped LDS: computed write, no atomic
    #pragma unroll
    for (int k = 0; k < C4; ++k)
        #pragma unroll
        for (int j = 0; j < 4; ++j) {
            unsigned int e = breg[k][j];
            if (e != 0xFFFFFFFFu) {
                unsigned int dl   = e & (BIN_NODES - 1);
                unsigned int rank = (e >> 23);
                ssrc[off[dl] + rank] = (e >> BIN_SHIFT) & 0x1FFFFu;
            }
        }
    __syncthreads();

    // 4) per-node gather + reduce: 4 nodes/wave (16-lane groups), 2-way unroll
    {
        const int sub = lane >> 4, sl = lane & 15;
        #pragma unroll
        for (int r = 0; r < 2; ++r) {
            int dl = w * 8 + r * 4 + sub;           // wave w owns nodes w*8..w*8+7
            unsigned int o0 = off[dl], o1 = off[dl + 1];
            float a0 = 0.f, a1 = 0.f, a2 = 0.f, a3 = 0.f;
            unsigned int i = o0 + sl;
            for (; i + 16 < o1; i += 32) {          // two independent gathers/iter
                unsigned int sA = ssrc[i];
                unsigned int sB = ssrc[i + 16];
                float4 xa = *reinterpret_cast<const float4*>(x + (size_t)sA * 4);
                float4 xb = *reinterpret_cast<const float4*>(x + (size_t)sB * 4);
                a0 += xa.x + xb.x; a1 += xa.y + xb.y;
                a2 += xa.z + xb.z; a3 += xa.w + xb.w;
            }
            if (i < o1) {
                unsigned int sA = ssrc[i];
                float4 xa = *reinterpret_cast<const float4*>(x + (size_t)sA * 4);
                a0 += xa.x; a1 += xa.y; a2 += xa.z; a3 += xa.w;
            }
            #pragma unroll
            for (int d = 8; d >= 1; d >>= 1) {
                a0 += __shfl_xor(a0, d, 16);
                a1 += __shfl_xor(a1, d, 16);
                a2 += __shfl_xor(a2, d, 16);
                a3 += __shfl_xor(a3, d, 16);
            }
            if (sl == 0) {
                lagg[dl][0] = a0; lagg[dl][1] = a1;
                lagg[dl][2] = a2; lagg[dl][3] = a3;
            }
        }
    }
    __syncthreads();

    // 5) MLP + pool; fast path when the wave's whole 8-node strip is one segment
    const int j = lane;
    const float w1c0 = W1[0 * HID + j], w1c1 = W1[1 * HID + j];
    const float w1c2 = W1[2 * HID + j], w1c3 = W1[3 * HID + j];
    const float b1j = b1[j];

    {
        int v0 = n0 + w * 8;
        int vlast = min(v0 + 7, N_NODES - 1);
        int nvalid = (v0 < N_NODES) ? (min(v0 + 7, N_NODES - 1) - v0 + 1) : 0;
        int g0 = batch[min(v0, N_NODES - 1)];
        int g1 = batch[vlast];

        if (nvalid > 0 && g0 == g1 && (g0 - base_g) < MAXSEG) {
            // ---- uniform-segment fast path: one psum RMW for the strip ----
            float hacc = 0.0f;
            for (int vl = 0; vl < nvalid; ++vl) {
                int v = v0 + vl;
                float h = b1j;
                h = fmaf(x[(size_t)v * 4 + 0] + lagg[w * 8 + vl][0], w1c0, h);
                h = fmaf(x[(size_t)v * 4 + 1] + lagg[w * 8 + vl][1], w1c1, h);
                h = fmaf(x[(size_t)v * 4 + 2] + lagg[w * 8 + vl][2], w1c2, h);
                h = fmaf(x[(size_t)v * 4 + 3] + lagg[w * 8 + vl][3], w1c3, h);
                hacc += fmaxf(h, 0.0f);
            }
            int seg = g0 - base_g;
            psum[w][seg][j] += hacc;              // wave-private: no race
            if (j == 0) pcnt[w][seg] += (float)nvalid;
        } else if (nvalid > 0) {
            // ---- general path (r17) ----
            for (int vl = 0; vl < nvalid; ++vl) {
                int v = v0 + vl;
                float h = b1j;
                h = fmaf(x[(size_t)v * 4 + 0] + lagg[w * 8 + vl][0], w1c0, h);
                h = fmaf(x[(size_t)v * 4 + 1] + lagg[w * 8 + vl][1], w1c1, h);
                h = fmaf(x[(size_t)v * 4 + 2] + lagg[w * 8 + vl][2], w1c2, h);
                h = fmaf(x[(size_t)v * 4 + 3] + lagg[w * 8 + vl][3], w1c3, h);
                h = fmaxf(h, 0.0f);
                int g = batch[v];
                int seg = g - base_g;
                if (seg < MAXSEG) {
                    psum[w][seg][j] += h;
                    if (j == 0) pcnt[w][seg] += 1.0f;
                } else {
                    unsafeAtomicAdd(&gsum[(size_t)g * HID + j], h);
                    if (j == 0) unsafeAtomicAdd(&gcnt[g], 1.0f);
                }
            }
        }
    }
    __syncthreads();

    // flush: waves 0..3 each own one segment, summing all 8 replicas
    if (w < MAXSEG) {
        int seg = w;
        float v8 = 0.0f;
        #pragma unroll
        for (int r = 0; r < NW; ++r) v8 += psum[r][seg][j];
        if (v8 != 0.0f)
            unsafeAtomicAdd(&gsum[(size_t)(base_g + seg) * HID + j], v8);
    }
    if (tid < MAXSEG) {
        float c = 0.0f;
        #pragma unroll
        for (int r = 0; r < NW; ++r) c += pcnt[r][tid];
        if (c > 0.0f)
            unsafeAtomicAdd(&gcnt[base_g + tid], c);
    }
}

// ---------------------------------------------------------------------------
// Kernel C: per graph g (W2/head hoisted past the mean pool by linearity).
// ---------------------------------------------------------------------------
__global__ void finalize(const float* __restrict__ gsum, const float* __restrict__ gcnt,
                         const float* __restrict__ W2, const float* __restrict__ b2,
                         const float* __restrict__ Wlin, const float* __restrict__ blin,
                         float* __restrict__ out) {
    int g = blockIdx.x;
    int j = threadIdx.x;  // 0..127
    __shared__ float pooled[HID];

    float cnt = gcnt[g];
    float inv = 1.0f / fmaxf(cnt, 1.0f);

    if (j < HID) {
        float s = cnt * b2[j];
        #pragma unroll 8
        for (int k = 0; k < HID; ++k)
            s = fmaf(gsum[(size_t)g * HID + k], W2[k * HID + j], s);
        pooled[j] = s * inv;
    }
    __syncthreads();

    float o = blin[j];
    #pragma unroll 8
    for (int k = 0; k < HID; ++k)
        o = fmaf(pooled[k], Wlin[k * OUT_DIM + j], o);
    out[(size_t)g * OUT_DIM + j] = o;
}

// ------------------------- fallback (round-2) path -------------------------
__global__ void edge_scatter(const int* __restrict__ src, const int* __restrict__ dst,
                             const float* __restrict__ x, float* __restrict__ agg) {
    int stride = gridDim.x * blockDim.x;
    for (int e = blockIdx.x * blockDim.x + threadIdx.x; e < N_EDGES; e += stride) {
        int s = src[e];
        int d = dst[e];
        float4 xv = *reinterpret_cast<const float4*>(x + (size_t)s * 4);
        float* a = agg + (size_t)d * 4;
        unsafeAtomicAdd(a + 0, xv.x);
        unsafeAtomicAdd(a + 1, xv.y);
        unsafeAtomicAdd(a + 2, xv.z);
        unsafeAtomicAdd(a + 3, xv.w);
    }
}

__global__ void node_mlp_pool(const float* __restrict__ x, const float* __restrict__ agg,
                              const int* __restrict__ batch,
                              const float* __restrict__ W1, const float* __restrict__ b1,
                              float* __restrict__ gsum, float* __restrict__ gcnt) {
    int j = threadIdx.x & 63;
    int local = threadIdx.x >> 6;
    int v = blockIdx.x * 4 + local;
    if (v >= N_NODES) return;
    float4 xv = *reinterpret_cast<const float4*>(x + (size_t)v * 4);
    float4 av = *reinterpret_cast<const float4*>(agg + (size_t)v * 4);
    float h = b1[j];
    h = fmaf(xv.x + av.x, W1[0 * HID + j], h);
    h = fmaf(xv.y + av.y, W1[1 * HID + j], h);
    h = fmaf(xv.z + av.z, W1[2 * HID + j], h);
    h = fmaf(xv.w + av.w, W1[3 * HID + j], h);
    h = fmaxf(h, 0.0f);
    int g = batch[v];
    unsafeAtomicAdd(&gsum[(size_t)g * HID + j], h);
    if (j == 0) unsafeAtomicAdd(&gcnt[g], 1.0f);
}

extern "C" void kernel_launch(void* const* d_in, const int* in_sizes, int n_in,
                              void* d_out, int out_size, void* d_ws, size_t ws_size,
                              hipStream_t stream) {
    const float* x    = (const float*)d_in[0];
    const int*   ei   = (const int*)d_in[1];
    const int*   bat  = (const int*)d_in[2];
    const float* W1   = (const float*)d_in[3];
    const float* b1   = (const float*)d_in[4];
    const float* W2   = (const float*)d_in[5];
    const float* b2   = (const float*)d_in[6];
    const float* Wlin = (const float*)d_in[7];
    const float* blin = (const float*)d_in[8];
    float* out = (float*)d_out;

    const int* src  = ei;             // edge_index[0]
    const int* dstp = ei + N_EDGES;   // edge_index[1]

    char* ws = (char*)d_ws;
    // layout: gsum[131072] gcnt[2048] cursor[6252 -> pad 6272] binned[NB*CAP*4] pad[16K]
    const size_t GSUM_OFF = 0, GCNT_OFF = 131072, CUR_OFF = 133120, BIN_OFF = 139392;
    const size_t NEED = BIN_OFF + (size_t)NB * CAP * 4 + 16384;   // ~32.2 MB

    if (ws_size >= NEED) {
        float* gsum = (float*)(ws + GSUM_OFF);
        float* gcnt = (float*)(ws + GCNT_OFF);
        unsigned int* cursor = (unsigned int*)(ws + CUR_OFF);
        unsigned int* binned = (unsigned int*)(ws + BIN_OFF);

        hipMemsetAsync(d_ws, 0, BIN_OFF, stream);  // gsum+gcnt+cursor

        scatter_bin<<<SCB, SCT, 0, stream>>>(src, dstp, cursor, binned);
        bin_mlp_pool<<<NB, BMT, 0, stream>>>(binned, cursor, x, bat, W1, b1, gsum, gcnt);
        finalize<<<N_GRAPHS, OUT_DIM, 0, stream>>>(gsum, gcnt, W2, b2, Wlin, blin, out);
    } else {
        // fallback: round-2 pipeline (needs ~1.74 MB)
        float* agg  = (float*)(ws);
        float* gsum = (float*)(ws + 1600000);
        float* gcnt = (float*)(ws + 1600000 + 131072);
        hipMemsetAsync(d_ws, 0, 1600000 + 131072 + 2048, stream);
        edge_scatter<<<4096, 256, 0, stream>>>(src, dstp, x, agg);
        node_mlp_pool<<<(N_NODES + 3) / 4, 256, 0, stream>>>(x, agg, bat, W1, b1, gsum, gcnt);
        finalize<<<N_GRAPHS, OUT_DIM, 0, stream>>>(gsum, gcnt, W2, b2, Wlin, blin, out);
    }
}

// Round 20
// 84.360 us; speedup vs baseline: 1.0369x; 1.0089x over previous
//
#include <hip/hip_runtime.h>
#include <hip/hip_bf16.h>

#define N_NODES  100000
#define N_EDGES  6400000
#define N_GRAPHS 512
#define HID      64
#define OUT_DIM  128

// binning params (64-node bins)
#define BIN_SHIFT 6
#define BIN_NODES 64
#define NB 1563                            // ceil(100000/64)
#define CAP 5120                           // slots per bin (mean 4096, +16 sigma)
#define MAXSEG 4

// scatter params (512 fat blocks)
#define SCB 512
#define SCT 1024
#define SCH (N_EDGES / SCB)                // 12500 exactly
#define SEGB ((NB + 15) / 16)              // 98 bins per wave segment
#define ITERS 13                           // ceil(12500/1024)
#define FULLI 12                           // iterations that are always in-bounds

// consumer params
#define BMT 512
#define NW  8
#define C4 3                               // uint4 loads: 3*2048*4 covers CAP

// ---------------------------------------------------------------------------
// Kernel S (r13 producer + guard trims): block counting-sort by dst bin,
// src/dst in registers, two LDS atomic passes, coalesced run copy.
// ---------------------------------------------------------------------------
__global__ void __launch_bounds__(SCT)
scatter_bin(const int* __restrict__ src, const int* __restrict__ dst,
            unsigned int* __restrict__ cursor, unsigned int* __restrict__ binned) {
    __shared__ unsigned int hist[NB];      // counts -> excl base -> run cnt -> incl
    __shared__ unsigned int gbase[NB];
    __shared__ unsigned int sorted[SCH];   // 50 KB
    __shared__ unsigned int wtot[16];

    const int tid = threadIdx.x, lane = tid & 63, w = tid >> 6;
    const int e0 = blockIdx.x * SCH;

    int dreg[ITERS], sreg[ITERS];
    #pragma unroll
    for (int k = 0; k < FULLI; ++k) {      // always in-bounds (12*1024 < 12500)
        int idx = k * SCT + tid;
        dreg[k] = dst[e0 + idx]; sreg[k] = src[e0 + idx];
    }
    {
        int idx = FULLI * SCT + tid;
        if (idx < SCH) { dreg[FULLI] = dst[e0 + idx]; sreg[FULLI] = src[e0 + idx]; }
        else           { dreg[FULLI] = -1;            sreg[FULLI] = 0; }
    }

    for (int i = tid; i < NB; i += SCT) hist[i] = 0u;
    __syncthreads();

    // A) histogram (plain atomic; hot 12 unconditional)
    #pragma unroll
    for (int k = 0; k < FULLI; ++k)
        atomicAdd(&hist[dreg[k] >> BIN_SHIFT], 1u);
    if (dreg[FULLI] >= 0) atomicAdd(&hist[dreg[FULLI] >> BIN_SHIFT], 1u);
    __syncthreads();

    // B) exclusive scan + reserve global ranges
    const int s0 = w * SEGB;
    const int s1 = min(s0 + SEGB, NB);
    unsigned int carry = 0u;
    for (int base = s0; base < s1; base += 64) {
        int i = base + lane;
        bool ok = (i < s1);
        unsigned int v = ok ? hist[i] : 0u;
        if (ok && v)
            gbase[i] = (unsigned int)i * CAP + atomicAdd(&cursor[i], v);
        unsigned int xi = v;
        #pragma unroll
        for (int d = 1; d < 64; d <<= 1) {
            unsigned int u = __shfl_up(xi, d, 64);
            if (lane >= d) xi += u;
        }
        if (ok) hist[i] = carry + xi - v;
        carry += __shfl(xi, 63, 64);
    }
    if (lane == 0) wtot[w] = carry;
    __syncthreads();
    if (w == 0 && lane < 16) {
        unsigned int v = wtot[lane], xi = v;
        #pragma unroll
        for (int d = 1; d < 16; d <<= 1) {
            unsigned int u = __shfl_up(xi, d, 64);
            if (lane >= d) xi += u;
        }
        wtot[lane] = xi - v;
    }
    __syncthreads();
    {
        unsigned int woff = wtot[w];
        for (int i = s0 + lane; i < s1; i += 64) hist[i] += woff;
    }
    __syncthreads();

    // C) reorder into LDS (hot 12 unconditional)
    #pragma unroll
    for (int k = 0; k < FULLI; ++k) {
        int b = dreg[k] >> BIN_SHIFT;
        unsigned int slot = atomicAdd(&hist[b], 1u);
        sorted[slot] = ((unsigned int)sreg[k] << BIN_SHIFT)
                     | (unsigned int)(dreg[k] & (BIN_NODES - 1));
    }
    if (dreg[FULLI] >= 0) {
        int b = dreg[FULLI] >> BIN_SHIFT;
        unsigned int slot = atomicAdd(&hist[b], 1u);
        sorted[slot] = ((unsigned int)sreg[FULLI] << BIN_SHIFT)
                     | (unsigned int)(dreg[FULLI] & (BIN_NODES - 1));
    }
    __syncthreads();

    // D) coalesced run copy (guard hoisted out of the element loop)
    const int sub = lane >> 3, le = lane & 7;
    for (int bb = s0 + sub; bb < s1; bb += 8) {
        unsigned int lo = (bb == 0) ? 0u : hist[bb - 1];
        unsigned int hi = hist[bb];
        unsigned int len = hi - lo;
        if (len == 0u) continue;
        unsigned int gb  = gbase[bb];
        unsigned int end = (unsigned int)(bb + 1) * CAP;
        unsigned int len2 = min(len, end > gb ? end - gb : 0u);
        for (unsigned int t = le; t < len2; t += 8)
            binned[gb + t] = sorted[lo + t];
    }
}

// ---------------------------------------------------------------------------
// Kernel B (r19 consumer, k=2 payload load gated on cnt to trim over-read).
// ---------------------------------------------------------------------------
__global__ void __launch_bounds__(BMT)
bin_mlp_pool(const unsigned int* __restrict__ binned,
             const unsigned int* __restrict__ cursor,
             const float* __restrict__ x, const int* __restrict__ batch,
             const float* __restrict__ W1, const float* __restrict__ b1,
             float* __restrict__ gsum, float* __restrict__ gcnt) {
    const int b   = blockIdx.x;
    const int n0  = b << BIN_SHIFT;
    const int tid = threadIdx.x;
    const int lane = tid & 63;
    const int w    = tid >> 6;          // wave 0..7

    __shared__ unsigned int hist[BIN_NODES];
    __shared__ unsigned int off[BIN_NODES + 1];
    __shared__ unsigned int ssrc[CAP];                  // 20 KB
    __shared__ float lagg[BIN_NODES][4];
    __shared__ float psum[NW][MAXSEG][HID];             // 8 KB, wave-private
    __shared__ float pcnt[NW][MAXSEG];

    // --- issue global loads first; k<2 unconditional (covers mean 4096) ---
    const unsigned int cnt_raw = cursor[b];
    const unsigned int* bp = binned + (size_t)b * CAP;
    uint4 v4[C4];
    #pragma unroll
    for (int k = 0; k < 2; ++k) {
        unsigned int i0 = (unsigned int)k * (BMT * 4) + (unsigned int)(tid << 2);
        v4[k] = *reinterpret_cast<const uint4*>(bp + i0);
    }
    const int base_g = batch[n0];

    // --- LDS init overlaps the in-flight loads ---
    if (tid < BIN_NODES) hist[tid] = 0u;
    for (int i = tid; i < NW * MAXSEG * HID; i += BMT) ((float*)psum)[i] = 0.0f;
    if (tid < NW * MAXSEG) ((float*)pcnt)[tid] = 0.0f;

    unsigned int cnt = cnt_raw > CAP ? CAP : cnt_raw;   // safety clamp
    {   // tail loads only when this bin actually spills past 4096 entries
        unsigned int i0 = 2u * (BMT * 4) + (unsigned int)(tid << 2);
        if (i0 < cnt) v4[2] = *reinterpret_cast<const uint4*>(bp + i0);
        else          v4[2] = make_uint4(0u, 0u, 0u, 0u);
    }
    __syncthreads();

    // 1) histogram; rank packed into bits 23..31
    unsigned int breg[C4][4];
    #pragma unroll
    for (int k = 0; k < C4; ++k) {
        unsigned int i0 = (unsigned int)k * (BMT * 4) + (unsigned int)(tid << 2);
        breg[k][0] = v4[k].x; breg[k][1] = v4[k].y;
        breg[k][2] = v4[k].z; breg[k][3] = v4[k].w;
        #pragma unroll
        for (int j = 0; j < 4; ++j) {
            if (i0 + j < cnt) {
                unsigned int r = atomicAdd(&hist[breg[k][j] & (BIN_NODES - 1)], 1u);
                breg[k][j] |= (r << 23);
            } else breg[k][j] = 0xFFFFFFFFu;
        }
    }
    __syncthreads();

    // 2) prefix scan (wave 0): off[dl] = exclusive base
    if (tid < BIN_NODES) {
        unsigned int v = hist[tid];
        #pragma unroll
        for (int d = 1; d < 64; d <<= 1) {
            unsigned int u = __shfl_up(v, d, 64);
            if (lane >= d) v += u;
        }
        off[tid + 1] = v;
        if (tid == 0) off[0] = 0u;
    }
    __syncthreads();

    // 3) reorder src into node-grouped LDS: computed write, no atomic
    #pragma unroll
    for (int k = 0; k < C4; ++k)
        #pragma unroll
        for (int j = 0; j < 4; ++j) {
            unsigned int e = breg[k][j];
            if (e != 0xFFFFFFFFu) {
                unsigned int dl   = e & (BIN_NODES - 1);
                unsigned int rank = (e >> 23);
                ssrc[off[dl] + rank] = (e >> BIN_SHIFT) & 0x1FFFFu;
            }
        }
    __syncthreads();

    // 4) per-node gather + reduce: 4 nodes/wave (16-lane groups), 2-way unroll
    {
        const int sub = lane >> 4, sl = lane & 15;
        #pragma unroll
        for (int r = 0; r < 2; ++r) {
            int dl = w * 8 + r * 4 + sub;           // wave w owns nodes w*8..w*8+7
            unsigned int o0 = off[dl], o1 = off[dl + 1];
            float a0 = 0.f, a1 = 0.f, a2 = 0.f, a3 = 0.f;
            unsigned int i = o0 + sl;
            for (; i + 16 < o1; i += 32) {          // two independent gathers/iter
                unsigned int sA = ssrc[i];
                unsigned int sB = ssrc[i + 16];
                float4 xa = *reinterpret_cast<const float4*>(x + (size_t)sA * 4);
                float4 xb = *reinterpret_cast<const float4*>(x + (size_t)sB * 4);
                a0 += xa.x + xb.x; a1 += xa.y + xb.y;
                a2 += xa.z + xb.z; a3 += xa.w + xb.w;
            }
            if (i < o1) {
                unsigned int sA = ssrc[i];
                float4 xa = *reinterpret_cast<const float4*>(x + (size_t)sA * 4);
                a0 += xa.x; a1 += xa.y; a2 += xa.z; a3 += xa.w;
            }
            #pragma unroll
            for (int d = 8; d >= 1; d >>= 1) {
                a0 += __shfl_xor(a0, d, 16);
                a1 += __shfl_xor(a1, d, 16);
                a2 += __shfl_xor(a2, d, 16);
                a3 += __shfl_xor(a3, d, 16);
            }
            if (sl == 0) {
                lagg[dl][0] = a0; lagg[dl][1] = a1;
                lagg[dl][2] = a2; lagg[dl][3] = a3;
            }
        }
    }
    __syncthreads();

    // 5) MLP + pool; fast path when the wave's whole 8-node strip is one segment
    const int j = lane;
    const float w1c0 = W1[0 * HID + j], w1c1 = W1[1 * HID + j];
    const float w1c2 = W1[2 * HID + j], w1c3 = W1[3 * HID + j];
    const float b1j = b1[j];

    {
        int v0 = n0 + w * 8;
        int vlast = min(v0 + 7, N_NODES - 1);
        int nvalid = (v0 < N_NODES) ? (min(v0 + 7, N_NODES - 1) - v0 + 1) : 0;
        int g0 = batch[min(v0, N_NODES - 1)];
        int g1 = batch[vlast];

        if (nvalid > 0 && g0 == g1 && (g0 - base_g) < MAXSEG) {
            float hacc = 0.0f;
            for (int vl = 0; vl < nvalid; ++vl) {
                int v = v0 + vl;
                float h = b1j;
                h = fmaf(x[(size_t)v * 4 + 0] + lagg[w * 8 + vl][0], w1c0, h);
                h = fmaf(x[(size_t)v * 4 + 1] + lagg[w * 8 + vl][1], w1c1, h);
                h = fmaf(x[(size_t)v * 4 + 2] + lagg[w * 8 + vl][2], w1c2, h);
                h = fmaf(x[(size_t)v * 4 + 3] + lagg[w * 8 + vl][3], w1c3, h);
                hacc += fmaxf(h, 0.0f);
            }
            int seg = g0 - base_g;
            psum[w][seg][j] += hacc;              // wave-private: no race
            if (j == 0) pcnt[w][seg] += (float)nvalid;
        } else if (nvalid > 0) {
            for (int vl = 0; vl < nvalid; ++vl) {
                int v = v0 + vl;
                float h = b1j;
                h = fmaf(x[(size_t)v * 4 + 0] + lagg[w * 8 + vl][0], w1c0, h);
                h = fmaf(x[(size_t)v * 4 + 1] + lagg[w * 8 + vl][1], w1c1, h);
                h = fmaf(x[(size_t)v * 4 + 2] + lagg[w * 8 + vl][2], w1c2, h);
                h = fmaf(x[(size_t)v * 4 + 3] + lagg[w * 8 + vl][3], w1c3, h);
                h = fmaxf(h, 0.0f);
                int g = batch[v];
                int seg = g - base_g;
                if (seg < MAXSEG) {
                    psum[w][seg][j] += h;
                    if (j == 0) pcnt[w][seg] += 1.0f;
                } else {
                    unsafeAtomicAdd(&gsum[(size_t)g * HID + j], h);
                    if (j == 0) unsafeAtomicAdd(&gcnt[g], 1.0f);
                }
            }
        }
    }
    __syncthreads();

    // flush: waves 0..3 each own one segment, summing all 8 replicas
    if (w < MAXSEG) {
        int seg = w;
        float v8 = 0.0f;
        #pragma unroll
        for (int r = 0; r < NW; ++r) v8 += psum[r][seg][j];
        if (v8 != 0.0f)
            unsafeAtomicAdd(&gsum[(size_t)(base_g + seg) * HID + j], v8);
    }
    if (tid < MAXSEG) {
        float c = 0.0f;
        #pragma unroll
        for (int r = 0; r < NW; ++r) c += pcnt[r][tid];
        if (c > 0.0f)
            unsafeAtomicAdd(&gcnt[base_g + tid], c);
    }
}

// ---------------------------------------------------------------------------
// Kernel C: per graph g (W2/head hoisted past the mean pool by linearity).
// ---------------------------------------------------------------------------
__global__ void finalize(const float* __restrict__ gsum, const float* __restrict__ gcnt,
                         const float* __restrict__ W2, const float* __restrict__ b2,
                         const float* __restrict__ Wlin, const float* __restrict__ blin,
                         float* __restrict__ out) {
    int g = blockIdx.x;
    int j = threadIdx.x;  // 0..127
    __shared__ float pooled[HID];

    float cnt = gcnt[g];
    float inv = 1.0f / fmaxf(cnt, 1.0f);

    if (j < HID) {
        float s = cnt * b2[j];
        #pragma unroll 8
        for (int k = 0; k < HID; ++k)
            s = fmaf(gsum[(size_t)g * HID + k], W2[k * HID + j], s);
        pooled[j] = s * inv;
    }
    __syncthreads();

    float o = blin[j];
    #pragma unroll 8
    for (int k = 0; k < HID; ++k)
        o = fmaf(pooled[k], Wlin[k * OUT_DIM + j], o);
    out[(size_t)g * OUT_DIM + j] = o;
}

// ------------------------- fallback (round-2) path -------------------------
__global__ void edge_scatter(const int* __restrict__ src, const int* __restrict__ dst,
                             const float* __restrict__ x, float* __restrict__ agg) {
    int stride = gridDim.x * blockDim.x;
    for (int e = blockIdx.x * blockDim.x + threadIdx.x; e < N_EDGES; e += stride) {
        int s = src[e];
        int d = dst[e];
        float4 xv = *reinterpret_cast<const float4*>(x + (size_t)s * 4);
        float* a = agg + (size_t)d * 4;
        unsafeAtomicAdd(a + 0, xv.x);
        unsafeAtomicAdd(a + 1, xv.y);
        unsafeAtomicAdd(a + 2, xv.z);
        unsafeAtomicAdd(a + 3, xv.w);
    }
}

__global__ void node_mlp_pool(const float* __restrict__ x, const float* __restrict__ agg,
                              const int* __restrict__ batch,
                              const float* __restrict__ W1, const float* __restrict__ b1,
                              float* __restrict__ gsum, float* __restrict__ gcnt) {
    int j = threadIdx.x & 63;
    int local = threadIdx.x >> 6;
    int v = blockIdx.x * 4 + local;
    if (v >= N_NODES) return;
    float4 xv = *reinterpret_cast<const float4*>(x + (size_t)v * 4);
    float4 av = *reinterpret_cast<const float4*>(agg + (size_t)v * 4);
    float h = b1[j];
    h = fmaf(xv.x + av.x, W1[0 * HID + j], h);
    h = fmaf(xv.y + av.y, W1[1 * HID + j], h);
    h = fmaf(xv.z + av.z, W1[2 * HID + j], h);
    h = fmaf(xv.w + av.w, W1[3 * HID + j], h);
    h = fmaxf(h, 0.0f);
    int g = batch[v];
    unsafeAtomicAdd(&gsum[(size_t)g * HID + j], h);
    if (j == 0) unsafeAtomicAdd(&gcnt[g], 1.0f);
}

extern "C" void kernel_launch(void* const* d_in, const int* in_sizes, int n_in,
                              void* d_out, int out_size, void* d_ws, size_t ws_size,
                              hipStream_t stream) {
    const float* x    = (const float*)d_in[0];
    const int*   ei   = (const int*)d_in[1];
    const int*   bat  = (const int*)d_in[2];
    const float* W1   = (const float*)d_in[3];
    const float* b1   = (const float*)d_in[4];
    const float* W2   = (const float*)d_in[5];
    const float* b2   = (const float*)d_in[6];
    const float* Wlin = (const float*)d_in[7];
    const float* blin = (const float*)d_in[8];
    float* out = (float*)d_out;

    const int* src  = ei;             // edge_index[0]
    const int* dstp = ei + N_EDGES;   // edge_index[1]

    char* ws = (char*)d_ws;
    // layout: gsum[131072] gcnt[2048] cursor[6252 -> pad 6272] binned[NB*CAP*4] pad[16K]
    const size_t GSUM_OFF = 0, GCNT_OFF = 131072, CUR_OFF = 133120, BIN_OFF = 139392;
    const size_t NEED = BIN_OFF + (size_t)NB * CAP * 4 + 16384;   // ~32.2 MB

    if (ws_size >= NEED) {
        float* gsum = (float*)(ws + GSUM_OFF);
        float* gcnt = (float*)(ws + GCNT_OFF);
        unsigned int* cursor = (unsigned int*)(ws + CUR_OFF);
        unsigned int* binned = (unsigned int*)(ws + BIN_OFF);

        hipMemsetAsync(d_ws, 0, BIN_OFF, stream);  // gsum+gcnt+cursor

        scatter_bin<<<SCB, SCT, 0, stream>>>(src, dstp, cursor, binned);
        bin_mlp_pool<<<NB, BMT, 0, stream>>>(binned, cursor, x, bat, W1, b1, gsum, gcnt);
        finalize<<<N_GRAPHS, OUT_DIM, 0, stream>>>(gsum, gcnt, W2, b2, Wlin, blin, out);
    } else {
        // fallback: round-2 pipeline (needs ~1.74 MB)
        float* agg  = (float*)(ws);
        float* gsum = (float*)(ws + 1600000);
        float* gcnt = (float*)(ws + 1600000 + 131072);
        hipMemsetAsync(d_ws, 0, 1600000 + 131072 + 2048, stream);
        edge_scatter<<<4096, 256, 0, stream>>>(src, dstp, x, agg);
        node_mlp_pool<<<(N_NODES + 3) / 4, 256, 0, stream>>>(x, agg, bat, W1, b1, gsum, gcnt);
        finalize<<<N_GRAPHS, OUT_DIM, 0, stream>>>(gsum, gcnt, W2, b2, Wlin, blin, out);
    }
}